// Round 2
// baseline (18404.829 us; speedup 1.0000x reference)
//
#include <hip/hip_runtime.h>

typedef __attribute__((ext_vector_type(8))) __bf16 bf16x8;
typedef __attribute__((ext_vector_type(4))) __bf16 bf16x4;
typedef __attribute__((ext_vector_type(4))) float f32x4;

#define OUT_HT (64ll*512*1024)
#define OUT_CT (OUT_HT + 64*1024)

// ---------------- prep: x fp32 -> bf16 (same [b][t][i] layout) ----------------
__global__ void convert_x(const float4* __restrict__ in, bf16x4* __restrict__ outp) {
    int i = blockIdx.x * 256 + threadIdx.x;      // 32768 * 256 threads, 1 float4 each
    float4 v = in[i];
    bf16x4 o;
    o[0] = (__bf16)v.x; o[1] = (__bf16)v.y; o[2] = (__bf16)v.z; o[3] = (__bf16)v.w;
    outp[i] = o;
}

// ------- prep: build W_comb [2048][4096] bf16 in MFMA-fragment-swizzled order -------
// element (k, n): n = h*4+g ; k<1024 -> W_x{g}[k][h], else W_h{g}[k-1024][h]
// frag order: wf[(((ng*64 + kc)*64 + l)<<3) + j], kc=k>>5, quad=(k>>3)&3, j=k&7,
//             ng=n>>4, l=quad*16 + (n&15)   (B frag: lane holds col n=l&15, k=(l>>4)*8+j)
__global__ void build_w(const float* __restrict__ Wxi, const float* __restrict__ Whi,
                        const float* __restrict__ Wxf, const float* __restrict__ Whf,
                        const float* __restrict__ Wxc, const float* __restrict__ Whc,
                        const float* __restrict__ Wxo, const float* __restrict__ Who,
                        __bf16* __restrict__ wf) {
    int idx = blockIdx.x * 256 + threadIdx.x;    // 32768 * 256 = 2048*4096
    int k = idx >> 12, n = idx & 4095;
    int h = n >> 2, g = n & 3;
    const float* W;
    if (k < 1024) W = (g == 0 ? Wxi : g == 1 ? Wxf : g == 2 ? Wxc : Wxo);
    else          W = (g == 0 ? Whi : g == 1 ? Whf : g == 2 ? Whc : Who);
    float v = W[(k & 1023) * 1024 + h];
    int kc = k >> 5, quad = (k >> 3) & 3, j = k & 7;
    int ng = n >> 4, l = quad * 16 + (n & 15);
    wf[((((ng * 64) + kc) * 64 + l) << 3) + j] = (__bf16)v;
}

// ---------------- grid barrier (no cooperative launch) ----------------
// generation barrier: arrival atomicAdd on cnt, last arrival resets cnt and bumps gen.
// Release: __threadfence() before arrival (h-stores written back device-wide).
// Acquire: __threadfence() after observing gen (invalidate local caches).
__device__ __forceinline__ void grid_barrier(int* cnt, int* gen, int tid, int& g_local) {
    __syncthreads();                 // all block threads' h-stores issued
    if (tid == 0) {
        __threadfence();             // make this block's writes device-visible
        int g = g_local;
        if (atomicAdd(cnt, 1) == 255) {
            atomicExch(cnt, 0);
            __threadfence();
            atomicAdd(gen, 1);       // release
        } else {
            while (__hip_atomic_load(gen, __ATOMIC_RELAXED, __HIP_MEMORY_SCOPE_AGENT) <= g)
                __builtin_amdgcn_s_sleep(2);
        }
        __threadfence();             // acquire: fresh view of other blocks' h
        g_local = g + 1;
    }
    __syncthreads();
}

// ---------------- persistent recurrent kernel ----------------
// 256 blocks x 256 threads (4 waves, guaranteed 1 block/CU co-residency).
// Block owns gate-cols n0=blk*16..+15 (= h-cols blk*4..+3, all 4 gates), all 64 batch rows.
__global__ void __launch_bounds__(256, 1) lstm_rnn(
    const __bf16* __restrict__ xbf,   // [64][512][1024]
    const __bf16* __restrict__ wf,    // frag-swizzled [256][64][64][8]
    const float* __restrict__ bi, const float* __restrict__ bfg,
    const float* __restrict__ bc, const float* __restrict__ bo,
    __bf16* __restrict__ hbuf,        // [2][64][1024]
    int* __restrict__ bar_cnt, int* __restrict__ bar_gen,
    float* __restrict__ out)
{
    const int blk = blockIdx.x, tid = threadIdx.x;
    const int wave = tid >> 6, lane = tid & 63;
    const int l15 = lane & 15, quad = lane >> 4;
    int g_local = 0;

    // preload this block's W fragments into registers: 64 chunks x 16B = 256 VGPR
    bf16x8 wfrag[64];
    const bf16x8* wsrc = (const bf16x8*)(wf + (size_t)blk * 64 * 64 * 8);
    #pragma unroll
    for (int kc = 0; kc < 64; ++kc)
        wfrag[kc] = wsrc[kc * 64 + lane];

    // zero h0 (harness poisons ws every launch) — 65536 elems over 65536 threads
    hbuf[blk * 256 + tid] = (__bf16)0.f;

    // pointwise ownership: thread -> (batch pb, local h-col phl); c stays in a register
    const int pb = tid >> 2, phl = tid & 3;
    const int hcol = blk * 4 + phl;
    const float bias_i = bi[hcol], bias_f = bfg[hcol],
                bias_c = bc[hcol], bias_o = bo[hcol];
    float c_reg = 0.f;

    __shared__ float gates[64 * 17];   // [batch][16 gate-cols], pad 17 vs conflicts

    const int brow = wave * 16 + l15;  // A-frag row = batch index
    const __bf16* xrow_base = xbf + ((size_t)brow * 512) * 1024 + quad * 8;

    grid_barrier(bar_cnt, bar_gen, tid, g_local);   // h0 visible everywhere

    int cur = 0;
    for (int t = 0; t < 512; ++t) {
        f32x4 acc0 = {0.f, 0.f, 0.f, 0.f}, acc1 = {0.f, 0.f, 0.f, 0.f};
        const __bf16* xrow = xrow_base + (size_t)t * 1024;
        const __bf16* hrow = hbuf + cur * 65536 + brow * 1024 + quad * 8;
        #pragma unroll
        for (int kc = 0; kc < 32; ++kc) {   // x part of K
            bf16x8 a = *(const bf16x8*)(xrow + kc * 32);
            acc0 = __builtin_amdgcn_mfma_f32_16x16x32_bf16(a, wfrag[kc], acc0, 0, 0, 0);
        }
        #pragma unroll
        for (int kc = 0; kc < 32; ++kc) {   // h part of K
            bf16x8 a = *(const bf16x8*)(hrow + kc * 32);
            acc1 = __builtin_amdgcn_mfma_f32_16x16x32_bf16(a, wfrag[32 + kc], acc1, 0, 0, 0);
        }
        // C/D frag: row = quad*4 + r (batch within wave tile), col = l15 (gate-col)
        #pragma unroll
        for (int r = 0; r < 4; ++r)
            gates[(wave * 16 + quad * 4 + r) * 17 + l15] = acc0[r] + acc1[r];
        __syncthreads();
        {
            float gi = gates[pb * 17 + phl * 4 + 0] + bias_i;
            float gf = gates[pb * 17 + phl * 4 + 1] + bias_f;
            float gc = gates[pb * 17 + phl * 4 + 2] + bias_c;
            float go = gates[pb * 17 + phl * 4 + 3] + bias_o;
            float it = 1.f / (1.f + __expf(-gi));
            float ft = 1.f / (1.f + __expf(-gf));
            float ch = tanhf(gc);
            float ot = 1.f / (1.f + __expf(-go));
            c_reg = ft * c_reg + it * ch;
            float hn = ot * tanhf(c_reg);
            hbuf[(cur ^ 1) * 65536 + pb * 1024 + hcol] = (__bf16)hn;
            out[((size_t)pb * 512 + t) * 1024 + hcol] = hn;
            if (t == 511) {
                out[OUT_HT + pb * 1024 + hcol] = hn;
                out[OUT_CT + pb * 1024 + hcol] = c_reg;
            }
        }
        grid_barrier(bar_cnt, bar_gen, tid, g_local);   // h(t) visible device-wide
        cur ^= 1;
    }
}

extern "C" void kernel_launch(void* const* d_in, const int* in_sizes, int n_in,
                              void* d_out, int out_size, void* d_ws, size_t ws_size,
                              hipStream_t stream) {
    const float* x   = (const float*)d_in[0];
    const float* Wxi = (const float*)d_in[1];
    const float* Whi = (const float*)d_in[2];
    const float* bi  = (const float*)d_in[3];
    const float* Wxf = (const float*)d_in[4];
    const float* Whf = (const float*)d_in[5];
    const float* bfg = (const float*)d_in[6];
    const float* Wxc = (const float*)d_in[7];
    const float* Whc = (const float*)d_in[8];
    const float* bc  = (const float*)d_in[9];
    const float* Wxo = (const float*)d_in[10];
    const float* Who = (const float*)d_in[11];
    const float* bo  = (const float*)d_in[12];
    float* out = (float*)d_out;

    char* ws = (char*)d_ws;
    __bf16* wcombF = (__bf16*)ws;                        // 16 MB
    __bf16* xbf    = (__bf16*)(ws + (16ll << 20));       // 64 MB
    __bf16* hbuf   = (__bf16*)(ws + (80ll << 20));       // 256 KB
    int*    bar    = (int*)(ws + (80ll << 20) + (512ll << 10)); // 2 ints

    hipMemsetAsync(bar, 0, 2 * sizeof(int), stream);

    hipLaunchKernelGGL(convert_x, dim3(32768), dim3(256), 0, stream,
                       (const float4*)x, (bf16x4*)xbf);
    hipLaunchKernelGGL(build_w, dim3(32768), dim3(256), 0, stream,
                       Wxi, Whi, Wxf, Whf, Wxc, Whc, Wxo, Who, wcombF);

    hipLaunchKernelGGL(lstm_rnn, dim3(256), dim3(256), 0, stream,
                       xbf, wcombF, bi, bfg, bc, bo, hbuf,
                       bar, bar + 1, out);
}

// Round 3
// 17762.206 us; speedup vs baseline: 1.0362x; 1.0362x over previous
//
#include <hip/hip_runtime.h>

typedef __attribute__((ext_vector_type(8))) __bf16 bf16x8;
typedef __attribute__((ext_vector_type(4))) __bf16 bf16x4;
typedef __attribute__((ext_vector_type(4))) float f32x4;

#define OUT_HT (64ll*512*1024)
#define OUT_CT (OUT_HT + 64*1024)

// ---------------- prep: x fp32 -> bf16 (same [b][t][i] layout) ----------------
__global__ void convert_x(const float4* __restrict__ in, bf16x4* __restrict__ outp) {
    int i = blockIdx.x * 256 + threadIdx.x;      // 32768 * 256 threads, 1 float4 each
    float4 v = in[i];
    bf16x4 o;
    o[0] = (__bf16)v.x; o[1] = (__bf16)v.y; o[2] = (__bf16)v.z; o[3] = (__bf16)v.w;
    outp[i] = o;
}

// ------- prep: build W_comb [2048][4096] bf16 in MFMA-fragment-swizzled order -------
// element (k, n): n = h*4+g ; k<1024 -> W_x{g}[k][h], else W_h{g}[k-1024][h]
// frag order: wf[(((ng*64 + kc)*64 + l)<<3) + j], kc=k>>5, quad=(k>>3)&3, j=k&7,
//             ng=n>>4, l=quad*16 + (n&15)   (B frag: lane holds col n=l&15, k=(l>>4)*8+j)
__global__ void build_w(const float* __restrict__ Wxi, const float* __restrict__ Whi,
                        const float* __restrict__ Wxf, const float* __restrict__ Whf,
                        const float* __restrict__ Wxc, const float* __restrict__ Whc,
                        const float* __restrict__ Wxo, const float* __restrict__ Who,
                        __bf16* __restrict__ wf) {
    int idx = blockIdx.x * 256 + threadIdx.x;    // 32768 * 256 = 2048*4096
    int k = idx >> 12, n = idx & 4095;
    int h = n >> 2, g = n & 3;
    const float* W;
    if (k < 1024) W = (g == 0 ? Wxi : g == 1 ? Wxf : g == 2 ? Wxc : Wxo);
    else          W = (g == 0 ? Whi : g == 1 ? Whf : g == 2 ? Whc : Who);
    float v = W[(k & 1023) * 1024 + h];
    int kc = k >> 5, quad = (k >> 3) & 3, j = k & 7;
    int ng = n >> 4, l = quad * 16 + (n & 15);
    wf[((((ng * 64) + kc) * 64 + l) << 3) + j] = (__bf16)v;
}

// ---------------- persistent recurrent kernel ----------------
// 256 blocks x 256 threads (4 waves, 1 block/CU co-resident by construction).
// Block owns gate-cols blk*16..+15 (= h-cols blk*4..+3, all 4 gates), all 64 batches.
//
// Barrier: 64 monotonic counters, one per 64B cacheline, 4 blocks arrive at
// counter (blk&63). Wave 0 lane l polls counter l (device-scope load, parallel
// across 64 lanes -> one L3 round trip per poll). Counter value 4*(t+1) means
// all blocks published h(t-1)'s successor... i.e. arrival #k is made after
// step k-2's h-store (init arrival = #1 after h0 zeroing).
__global__ void __launch_bounds__(256, 1) lstm_rnn(
    const __bf16* __restrict__ xbf,   // [64][512][1024]
    const __bf16* __restrict__ wf,    // frag-swizzled [256][64][64][8]
    const float* __restrict__ bi, const float* __restrict__ bfg,
    const float* __restrict__ bc, const float* __restrict__ bo,
    __bf16* __restrict__ hbuf,        // [2][64][1024]
    int* __restrict__ bar,            // 64 counters, 16-int stride (64B lines)
    float* __restrict__ out)
{
    const int blk = blockIdx.x, tid = threadIdx.x;
    const int wave = tid >> 6, lane = tid & 63;
    const int l15 = lane & 15, quad = lane >> 4;

    // preload this block's W fragments into registers: 64 chunks x 16B
    bf16x8 wfrag[64];
    const bf16x8* wsrc = (const bf16x8*)(wf + (size_t)blk * 64 * 64 * 8);
    #pragma unroll
    for (int kc = 0; kc < 64; ++kc)
        wfrag[kc] = wsrc[kc * 64 + lane];

    // zero h0 (ws is poisoned every launch) — 65536 elems over 65536 threads
    hbuf[blk * 256 + tid] = (__bf16)0.f;

    // pointwise ownership: thread -> (batch pb, local h-col phl); c in a register
    const int pb = tid >> 2, phl = tid & 3;
    const int hcol = blk * 4 + phl;
    const float bias_i = bi[hcol], bias_f = bfg[hcol],
                bias_c = bc[hcol], bias_o = bo[hcol];
    float c_reg = 0.f;

    __shared__ float gates[64 * 17];   // [batch][16 gate-cols], pad 17

    const int brow = wave * 16 + l15;  // A-frag row = batch index
    const __bf16* xrow_base = xbf + ((size_t)brow * 512) * 1024 + quad * 8;

    // arrival #1: h0 published
    __syncthreads();
    if (tid == 0) {
        __threadfence();
        __hip_atomic_fetch_add(&bar[(blk & 63) * 16], 1,
                               __ATOMIC_RELAXED, __HIP_MEMORY_SCOPE_AGENT);
    }

    int cur = 0;
    for (int t = 0; t < 512; ++t) {
        // ---- x-part: no h dependency, overlaps straggler skew ----
        f32x4 acc0a = {0.f,0.f,0.f,0.f}, acc0b = {0.f,0.f,0.f,0.f};
        const __bf16* xrow = xrow_base + (size_t)t * 1024;
        #pragma unroll
        for (int kc = 0; kc < 16; ++kc) {
            bf16x8 a0 = *(const bf16x8*)(xrow + (2*kc) * 32);
            bf16x8 a1 = *(const bf16x8*)(xrow + (2*kc+1) * 32);
            acc0a = __builtin_amdgcn_mfma_f32_16x16x32_bf16(a0, wfrag[2*kc],   acc0a, 0,0,0);
            acc0b = __builtin_amdgcn_mfma_f32_16x16x32_bf16(a1, wfrag[2*kc+1], acc0b, 0,0,0);
        }

        // ---- wait: all blocks published h(t-1) ----
        const int target = 4 * (t + 1);
        if (tid < 64) {
            while (__hip_atomic_load(&bar[tid * 16], __ATOMIC_RELAXED,
                                     __HIP_MEMORY_SCOPE_AGENT) < target)
                __builtin_amdgcn_s_sleep(2);
        }
        __syncthreads();
        __threadfence();   // acquire: invalidate stale h lines

        // ---- h-part ----
        f32x4 acc1a = {0.f,0.f,0.f,0.f}, acc1b = {0.f,0.f,0.f,0.f};
        const __bf16* hrow = hbuf + cur * 65536 + brow * 1024 + quad * 8;
        #pragma unroll
        for (int kc = 0; kc < 16; ++kc) {
            bf16x8 a0 = *(const bf16x8*)(hrow + (2*kc) * 32);
            bf16x8 a1 = *(const bf16x8*)(hrow + (2*kc+1) * 32);
            acc1a = __builtin_amdgcn_mfma_f32_16x16x32_bf16(a0, wfrag[32+2*kc],   acc1a, 0,0,0);
            acc1b = __builtin_amdgcn_mfma_f32_16x16x32_bf16(a1, wfrag[32+2*kc+1], acc1b, 0,0,0);
        }

        // C/D frag: row = quad*4 + r (batch within wave tile), col = l15 (gate-col)
        #pragma unroll
        for (int r = 0; r < 4; ++r)
            gates[(wave * 16 + quad * 4 + r) * 17 + l15] =
                acc0a[r] + acc0b[r] + acc1a[r] + acc1b[r];
        __syncthreads();
        {
            float gi = gates[pb * 17 + phl * 4 + 0] + bias_i;
            float gf = gates[pb * 17 + phl * 4 + 1] + bias_f;
            float gc = gates[pb * 17 + phl * 4 + 2] + bias_c;
            float go = gates[pb * 17 + phl * 4 + 3] + bias_o;
            float it = 1.f / (1.f + __expf(-gi));
            float ft = 1.f / (1.f + __expf(-gf));
            float ch = tanhf(gc);
            float ot = 1.f / (1.f + __expf(-go));
            c_reg = ft * c_reg + it * ch;
            float hn = ot * tanhf(c_reg);
            hbuf[(cur ^ 1) * 65536 + pb * 1024 + hcol] = (__bf16)hn;
            // nontemporal: avoid RFO + L2 dirtying; not needed device-visible
            __builtin_nontemporal_store(hn, &out[((size_t)pb * 512 + t) * 1024 + hcol]);
            if (t == 511) {
                __builtin_nontemporal_store(hn,    &out[OUT_HT + pb * 1024 + hcol]);
                __builtin_nontemporal_store(c_reg, &out[OUT_CT + pb * 1024 + hcol]);
            }
        }
        __syncthreads();   // all h-stores issued before release
        if (tid == 0) {
            __threadfence();   // release: h(t) device-visible
            __hip_atomic_fetch_add(&bar[(blk & 63) * 16], 1,
                                   __ATOMIC_RELAXED, __HIP_MEMORY_SCOPE_AGENT);
        }
        cur ^= 1;
    }
}

extern "C" void kernel_launch(void* const* d_in, const int* in_sizes, int n_in,
                              void* d_out, int out_size, void* d_ws, size_t ws_size,
                              hipStream_t stream) {
    const float* x   = (const float*)d_in[0];
    const float* Wxi = (const float*)d_in[1];
    const float* Whi = (const float*)d_in[2];
    const float* bi  = (const float*)d_in[3];
    const float* Wxf = (const float*)d_in[4];
    const float* Whf = (const float*)d_in[5];
    const float* bfg = (const float*)d_in[6];
    const float* Wxc = (const float*)d_in[7];
    const float* Whc = (const float*)d_in[8];
    const float* bc  = (const float*)d_in[9];
    const float* Wxo = (const float*)d_in[10];
    const float* Who = (const float*)d_in[11];
    const float* bo  = (const float*)d_in[12];
    float* out = (float*)d_out;

    char* ws = (char*)d_ws;
    __bf16* wcombF = (__bf16*)ws;                        // 16 MB
    __bf16* xbf    = (__bf16*)(ws + (16ll << 20));       // 64 MB
    __bf16* hbuf   = (__bf16*)(ws + (80ll << 20));       // 256 KB
    int*    bar    = (int*)(ws + (80ll << 20) + (512ll << 10)); // 64 x 64B

    hipMemsetAsync(bar, 0, 64 * 64, stream);

    hipLaunchKernelGGL(convert_x, dim3(32768), dim3(256), 0, stream,
                       (const float4*)x, (bf16x4*)xbf);
    hipLaunchKernelGGL(build_w, dim3(32768), dim3(256), 0, stream,
                       Wxi, Whi, Wxf, Whf, Wxc, Whc, Wxo, Who, wcombF);

    hipLaunchKernelGGL(lstm_rnn, dim3(256), dim3(256), 0, stream,
                       xbf, wcombF, bi, bfg, bc, bo, hbuf, bar, out);
}

// Round 4
// 8206.242 us; speedup vs baseline: 2.2428x; 2.1645x over previous
//
#include <hip/hip_runtime.h>

typedef __attribute__((ext_vector_type(8))) __bf16 bf16x8;
typedef __attribute__((ext_vector_type(4))) __bf16 bf16x4;
typedef __attribute__((ext_vector_type(4))) float f32x4;
typedef unsigned long long u64;

#define OUT_HT (64ll*512*1024)
#define OUT_CT (OUT_HT + 64*1024)

// ---------------- prep: x fp32 -> bf16 (same [b][t][i] layout) ----------------
__global__ void convert_x(const float4* __restrict__ in, bf16x4* __restrict__ outp) {
    int i = blockIdx.x * 256 + threadIdx.x;      // 32768 * 256 threads, 1 float4 each
    float4 v = in[i];
    bf16x4 o;
    o[0] = (__bf16)v.x; o[1] = (__bf16)v.y; o[2] = (__bf16)v.z; o[3] = (__bf16)v.w;
    outp[i] = o;
}

// ------- prep: build W_comb [2048][4096] bf16 in MFMA-fragment-swizzled order -------
// element (k, n): n = h*4+g ; k<1024 -> W_x{g}[k][h], else W_h{g}[k-1024][h]
// frag order: wf[(((ng*64 + kc)*64 + l)<<3) + j], kc=k>>5, quad=(k>>3)&3, j=k&7,
//             ng=n>>4, l=quad*16 + (n&15)   (B frag: lane holds col n=l&15, k=(l>>4)*8+j)
__global__ void build_w(const float* __restrict__ Wxi, const float* __restrict__ Whi,
                        const float* __restrict__ Wxf, const float* __restrict__ Whf,
                        const float* __restrict__ Wxc, const float* __restrict__ Whc,
                        const float* __restrict__ Wxo, const float* __restrict__ Who,
                        __bf16* __restrict__ wf) {
    int idx = blockIdx.x * 256 + threadIdx.x;    // 32768 * 256 = 2048*4096
    int k = idx >> 12, n = idx & 4095;
    int h = n >> 2, g = n & 3;
    const float* W;
    if (k < 1024) W = (g == 0 ? Wxi : g == 1 ? Wxf : g == 2 ? Wxc : Wxo);
    else          W = (g == 0 ? Whi : g == 1 ? Whf : g == 2 ? Whc : Who);
    float v = W[(k & 1023) * 1024 + h];
    int kc = k >> 5, quad = (k >> 3) & 3, j = k & 7;
    int ng = n >> 4, l = quad * 16 + (n & 15);
    wf[((((ng * 64) + kc) * 64 + l) << 3) + j] = (__bf16)v;
}

union HU { u64 u[2]; bf16x8 v; };

// ---------------- persistent recurrent kernel (fence-free) ----------------
// 256 blocks x 256 threads (4 waves, 1 block/CU). Block owns gate-cols
// blk*16..+15 (= h-cols blk*4..+3, all 4 gates), all 64 batches.
// Coherence protocol: h is exchanged ONLY via relaxed agent-scope atomic
// u64 stores/loads (bypass non-coherent L1/L2, land/read at the device
// coherence point). Ordering: store -> s_waitcnt(0) -> barrier -> relaxed
// atomic arrival; readers poll counters (relaxed agent) then load h
// (relaxed agent). NO __threadfence anywhere => no buffer_wbl2/inv.
__global__ void __launch_bounds__(256, 1) lstm_rnn(
    const __bf16* __restrict__ xbf,   // [64][512][1024]
    const __bf16* __restrict__ wf,    // frag-swizzled [256][64][64][8]
    const float* __restrict__ bi, const float* __restrict__ bfg,
    const float* __restrict__ bc, const float* __restrict__ bo,
    __bf16* __restrict__ hbuf,        // [2][64][1024]
    int* __restrict__ bar,            // 64 counters, 16-int stride (64B lines)
    float* __restrict__ out)
{
    const int blk = blockIdx.x, tid = threadIdx.x;
    const int wave = tid >> 6, lane = tid & 63;
    const int l15 = lane & 15, quad = lane >> 4;

    // preload this block's W fragments into registers: 64 chunks x 16B
    bf16x8 wfrag[64];
    const bf16x8* wsrc = (const bf16x8*)(wf + (size_t)blk * 64 * 64 * 8);
    #pragma unroll
    for (int kc = 0; kc < 64; ++kc)
        wfrag[kc] = wsrc[kc * 64 + lane];

    // zero h0 (buffer 0) coherently: 256 blocks x 64 lanes x 8B = 128 KB
    if (tid < 64)
        __hip_atomic_store(((u64*)hbuf) + blk * 64 + tid, 0ULL,
                           __ATOMIC_RELAXED, __HIP_MEMORY_SCOPE_AGENT);
    __builtin_amdgcn_s_waitcnt(0);
    __syncthreads();
    if (tid == 0)
        __hip_atomic_fetch_add(&bar[(blk & 63) * 16], 1,
                               __ATOMIC_RELAXED, __HIP_MEMORY_SCOPE_AGENT);

    // pointwise ownership: thread -> (batch pb, local h-col phl); c in a register
    const int pb = tid >> 2, phl = tid & 3;
    const int hcol = blk * 4 + phl;
    const float bias_i = bi[hcol], bias_f = bfg[hcol],
                bias_c = bc[hcol], bias_o = bo[hcol];
    float c_reg = 0.f;

    __shared__ float gates[64 * 17];   // [batch][16 gate-cols], pad 17
    __shared__ u64 hstage[64];         // packed 4x bf16 per batch row

    const int brow = wave * 16 + l15;  // A-frag row = batch index
    const __bf16* xrow_base = xbf + ((size_t)brow * 512) * 1024 + quad * 8;

    int cur = 0;
    for (int t = 0; t < 512; ++t) {
        // ---- x-part: no h dependency, overlaps straggler skew ----
        f32x4 acc0a = {0.f,0.f,0.f,0.f}, acc0b = {0.f,0.f,0.f,0.f};
        const __bf16* xrow = xrow_base + (size_t)t * 1024;
        #pragma unroll
        for (int kc = 0; kc < 16; ++kc) {
            bf16x8 a0 = *(const bf16x8*)(xrow + (2*kc) * 32);
            bf16x8 a1 = *(const bf16x8*)(xrow + (2*kc+1) * 32);
            acc0a = __builtin_amdgcn_mfma_f32_16x16x32_bf16(a0, wfrag[2*kc],   acc0a, 0,0,0);
            acc0b = __builtin_amdgcn_mfma_f32_16x16x32_bf16(a1, wfrag[2*kc+1], acc0b, 0,0,0);
        }

        // ---- wait: all blocks published h(t-1) ----
        const int target = 4 * (t + 1);
        if (tid < 64) {
            while (__hip_atomic_load(&bar[tid * 16], __ATOMIC_RELAXED,
                                     __HIP_MEMORY_SCOPE_AGENT) < target)
                __builtin_amdgcn_s_sleep(4);
        }
        __syncthreads();

        // ---- h-part: coherent u64 loads, batched ahead of the MFMAs ----
        f32x4 acc1a = {0.f,0.f,0.f,0.f}, acc1b = {0.f,0.f,0.f,0.f};
        const u64* hp = (const u64*)(hbuf + cur * 65536 + brow * 1024 + quad * 8);
        #pragma unroll
        for (int half = 0; half < 2; ++half) {
            u64 hr[32];
            #pragma unroll
            for (int i = 0; i < 16; ++i) {
                const u64* p = hp + (half * 16 + i) * 8;
                hr[2*i]   = __hip_atomic_load(p,     __ATOMIC_RELAXED, __HIP_MEMORY_SCOPE_AGENT);
                hr[2*i+1] = __hip_atomic_load(p + 1, __ATOMIC_RELAXED, __HIP_MEMORY_SCOPE_AGENT);
            }
            #pragma unroll
            for (int i = 0; i < 16; ++i) {
                HU hu; hu.u[0] = hr[2*i]; hu.u[1] = hr[2*i+1];
                if (i & 1)
                    acc1b = __builtin_amdgcn_mfma_f32_16x16x32_bf16(hu.v, wfrag[32 + half*16 + i], acc1b, 0,0,0);
                else
                    acc1a = __builtin_amdgcn_mfma_f32_16x16x32_bf16(hu.v, wfrag[32 + half*16 + i], acc1a, 0,0,0);
            }
        }

        // C/D frag: row = quad*4 + r (batch within wave tile), col = l15 (gate-col)
        #pragma unroll
        for (int r = 0; r < 4; ++r)
            gates[(wave * 16 + quad * 4 + r) * 17 + l15] =
                acc0a[r] + acc0b[r] + acc1a[r] + acc1b[r];
        __syncthreads();
        {
            float gi = gates[pb * 17 + phl * 4 + 0] + bias_i;
            float gf = gates[pb * 17 + phl * 4 + 1] + bias_f;
            float gc = gates[pb * 17 + phl * 4 + 2] + bias_c;
            float go = gates[pb * 17 + phl * 4 + 3] + bias_o;
            float it = 1.f / (1.f + __expf(-gi));
            float ft = 1.f / (1.f + __expf(-gf));
            float ch = tanhf(gc);
            float ot = 1.f / (1.f + __expf(-go));
            c_reg = ft * c_reg + it * ch;
            float hn = ot * tanhf(c_reg);
            ((__bf16*)&hstage[pb])[phl] = (__bf16)hn;
            __builtin_nontemporal_store(hn, &out[((size_t)pb * 512 + t) * 1024 + hcol]);
            if (t == 511) {
                __builtin_nontemporal_store(hn,    &out[OUT_HT + pb * 1024 + hcol]);
                __builtin_nontemporal_store(c_reg, &out[OUT_CT + pb * 1024 + hcol]);
            }
        }
        __syncthreads();   // hstage complete
        if (tid < 64) {
            // h(t) row tid, cols blk*4..+3 -> u64 index tid*256 + blk
            u64 hv = hstage[tid];
            __hip_atomic_store(((u64*)(hbuf + (cur ^ 1) * 65536)) + tid * 256 + blk,
                               hv, __ATOMIC_RELAXED, __HIP_MEMORY_SCOPE_AGENT);
        }
        __builtin_amdgcn_s_waitcnt(0);   // h stores at coherence point
        __syncthreads();
        if (tid == 0)
            __hip_atomic_fetch_add(&bar[(blk & 63) * 16], 1,
                                   __ATOMIC_RELAXED, __HIP_MEMORY_SCOPE_AGENT);
        cur ^= 1;
    }
}

extern "C" void kernel_launch(void* const* d_in, const int* in_sizes, int n_in,
                              void* d_out, int out_size, void* d_ws, size_t ws_size,
                              hipStream_t stream) {
    const float* x   = (const float*)d_in[0];
    const float* Wxi = (const float*)d_in[1];
    const float* Whi = (const float*)d_in[2];
    const float* bi  = (const float*)d_in[3];
    const float* Wxf = (const float*)d_in[4];
    const float* Whf = (const float*)d_in[5];
    const float* bfg = (const float*)d_in[6];
    const float* Wxc = (const float*)d_in[7];
    const float* Whc = (const float*)d_in[8];
    const float* bc  = (const float*)d_in[9];
    const float* Wxo = (const float*)d_in[10];
    const float* Who = (const float*)d_in[11];
    const float* bo  = (const float*)d_in[12];
    float* out = (float*)d_out;

    char* ws = (char*)d_ws;
    __bf16* wcombF = (__bf16*)ws;                        // 16 MB
    __bf16* xbf    = (__bf16*)(ws + (16ll << 20));       // 64 MB
    __bf16* hbuf   = (__bf16*)(ws + (80ll << 20));       // 256 KB
    int*    bar    = (int*)(ws + (80ll << 20) + (512ll << 10)); // 64 x 64B

    hipMemsetAsync(bar, 0, 64 * 64, stream);

    hipLaunchKernelGGL(convert_x, dim3(32768), dim3(256), 0, stream,
                       (const float4*)x, (bf16x4*)xbf);
    hipLaunchKernelGGL(build_w, dim3(32768), dim3(256), 0, stream,
                       Wxi, Whi, Wxf, Whf, Wxc, Whc, Wxo, Who, wcombF);

    hipLaunchKernelGGL(lstm_rnn, dim3(256), dim3(256), 0, stream,
                       xbf, wcombF, bi, bfg, bc, bo, hbuf, bar, out);
}

// Round 5
// 6503.305 us; speedup vs baseline: 2.8301x; 1.2619x over previous
//
#include <hip/hip_runtime.h>

typedef __attribute__((ext_vector_type(8))) __bf16 bf16x8;
typedef __attribute__((ext_vector_type(4))) __bf16 bf16x4;
typedef __attribute__((ext_vector_type(4))) float f32x4;
typedef unsigned long long u64;

#define OUT_HT (64ll*512*1024)
#define OUT_CT (OUT_HT + 64*1024)

// ---------------- prep: x fp32 -> bf16 (same [b][t][i] layout) ----------------
__global__ void convert_x(const float4* __restrict__ in, bf16x4* __restrict__ outp) {
    int i = blockIdx.x * 256 + threadIdx.x;      // 32768 * 256 threads, 1 float4 each
    float4 v = in[i];
    bf16x4 o;
    o[0] = (__bf16)v.x; o[1] = (__bf16)v.y; o[2] = (__bf16)v.z; o[3] = (__bf16)v.w;
    outp[i] = o;
}

// ------- prep: build W_comb [2048][4096] bf16 in MFMA-fragment-swizzled order -------
// element (k, n): n = h*4+g ; k<1024 -> W_x{g}[k][h], else W_h{g}[k-1024][h]
// frag order: wf[(((ng*64 + kc)*64 + l)<<3) + j], kc=k>>5, quad=(k>>3)&3, j=k&7,
//             ng=n>>4, l=quad*16 + (n&15)   (B frag: lane holds col n=l&15, k=(l>>4)*8+j)
__global__ void build_w(const float* __restrict__ Wxi, const float* __restrict__ Whi,
                        const float* __restrict__ Wxf, const float* __restrict__ Whf,
                        const float* __restrict__ Wxc, const float* __restrict__ Whc,
                        const float* __restrict__ Wxo, const float* __restrict__ Who,
                        __bf16* __restrict__ wf) {
    int idx = blockIdx.x * 256 + threadIdx.x;    // 32768 * 256 = 2048*4096
    int k = idx >> 12, n = idx & 4095;
    int h = n >> 2, g = n & 3;
    const float* W;
    if (k < 1024) W = (g == 0 ? Wxi : g == 1 ? Wxf : g == 2 ? Wxc : Wxo);
    else          W = (g == 0 ? Whi : g == 1 ? Whf : g == 2 ? Whc : Who);
    float v = W[(k & 1023) * 1024 + h];
    int kc = k >> 5, quad = (k >> 3) & 3, j = k & 7;
    int ng = n >> 4, l = quad * 16 + (n & 15);
    wf[((((ng * 64) + kc) * 64 + l) << 3) + j] = (__bf16)v;
}

// ---------------- persistent recurrent kernel (ring-buffer coherence) ----------------
// 256 blocks x 256 threads (4 waves, 1 block/CU). Block owns gate-cols
// blk*16..+15 (= h-cols blk*4..+3, all 4 gates), all 64 batches.
//
// h exchange: writers publish h(t+1) into ring slot (t+1)&63 with agent-scope
// (L2-bypassing) u64 atomic stores -> land at L3 (device coherence point).
// Readers use PLAIN vector loads: slot address untouched by this XCD's L1/L2
// for 64 steps (~16 MB of intervening fills vs 4 MB L2) -> no stale copy can
// exist, load must miss to L3. One __threadfence per block at START flushes
// harness-memset dirt from every XCD's L2 so it can never evict onto the ring.
__global__ void __launch_bounds__(256, 1) lstm_rnn(
    const __bf16* __restrict__ xbf,   // [64][512][1024]
    const __bf16* __restrict__ wf,    // frag-swizzled [256][64][64][8]
    const float* __restrict__ bi, const float* __restrict__ bfg,
    const float* __restrict__ bc, const float* __restrict__ bo,
    __bf16* __restrict__ ring,        // [64][64][1024] ring of h slots
    int* __restrict__ bar,            // 64 counters, 16-int stride (64B lines)
    float* __restrict__ out)
{
    const int blk = blockIdx.x, tid = threadIdx.x;
    const int wave = tid >> 6, lane = tid & 63;
    const int l15 = lane & 15, quad = lane >> 4;

    // preload this block's W fragments into registers: 64 chunks x 16B
    bf16x8 wfrag[64];
    const bf16x8* wsrc = (const bf16x8*)(wf + (size_t)blk * 64 * 64 * 8);
    #pragma unroll
    for (int kc = 0; kc < 64; ++kc)
        wfrag[kc] = wsrc[kc * 64 + lane];

    // ---- round 1: flush this XCD's L2 (memset-poison dirt) ----
    __threadfence();
    __syncthreads();
    if (tid == 0)
        __hip_atomic_fetch_add(&bar[(blk & 63) * 16], 1,
                               __ATOMIC_RELAXED, __HIP_MEMORY_SCOPE_AGENT);
    if (tid < 64) {
        while (__hip_atomic_load(&bar[tid * 16], __ATOMIC_RELAXED,
                                 __HIP_MEMORY_SCOPE_AGENT) < 4)
            __builtin_amdgcn_s_sleep(2);
    }
    __syncthreads();

    // ---- round 2: publish h0 = 0 into ring slot 0 (after all L2 flushes) ----
    if (tid < 64)
        __hip_atomic_store(((u64*)ring) + tid * 256 + blk, 0ULL,
                           __ATOMIC_RELAXED, __HIP_MEMORY_SCOPE_AGENT);
    __builtin_amdgcn_s_waitcnt(0);
    __syncthreads();
    if (tid == 0)
        __hip_atomic_fetch_add(&bar[(blk & 63) * 16], 1,
                               __ATOMIC_RELAXED, __HIP_MEMORY_SCOPE_AGENT);

    // pointwise ownership: thread -> (batch pb, local h-col phl); c in a register
    const int pb = tid >> 2, phl = tid & 3;
    const int hcol = blk * 4 + phl;
    const float bias_i = bi[hcol], bias_f = bfg[hcol],
                bias_c = bc[hcol], bias_o = bo[hcol];
    float c_reg = 0.f;

    __shared__ float gates[64 * 17];   // [batch][16 gate-cols], pad 17
    __shared__ u64 hstage[64];         // packed 4x bf16 per batch row

    const int brow = wave * 16 + l15;  // A-frag row = batch index
    const __bf16* xrow_base = xbf + ((size_t)brow * 512) * 1024 + quad * 8;

    for (int t = 0; t < 512; ++t) {
        // ---- x-part: no h dependency, overlaps straggler skew ----
        f32x4 acc0a = {0.f,0.f,0.f,0.f}, acc0b = {0.f,0.f,0.f,0.f};
        const __bf16* xrow = xrow_base + (size_t)t * 1024;
        #pragma unroll
        for (int kc = 0; kc < 16; ++kc) {
            bf16x8 a0 = *(const bf16x8*)(xrow + (2*kc) * 32);
            bf16x8 a1 = *(const bf16x8*)(xrow + (2*kc+1) * 32);
            acc0a = __builtin_amdgcn_mfma_f32_16x16x32_bf16(a0, wfrag[2*kc],   acc0a, 0,0,0);
            acc0b = __builtin_amdgcn_mfma_f32_16x16x32_bf16(a1, wfrag[2*kc+1], acc0b, 0,0,0);
        }

        // ---- wait: all blocks published h(t) (rounds = t+2, 4 blocks/counter) ----
        const int target = 4 * (t + 2);
        if (tid < 64) {
            while (__hip_atomic_load(&bar[tid * 16], __ATOMIC_RELAXED,
                                     __HIP_MEMORY_SCOPE_AGENT) < target)
                __builtin_amdgcn_s_sleep(2);
        }
        __syncthreads();

        // ---- h-part: PLAIN pipelined vector loads from cold ring slot ----
        f32x4 acc1a = {0.f,0.f,0.f,0.f}, acc1b = {0.f,0.f,0.f,0.f};
        const __bf16* hrow = ring + (size_t)(t & 63) * 65536 + brow * 1024 + quad * 8;
        #pragma unroll
        for (int kc = 0; kc < 16; ++kc) {
            bf16x8 a0 = *(const bf16x8*)(hrow + (2*kc) * 32);
            bf16x8 a1 = *(const bf16x8*)(hrow + (2*kc+1) * 32);
            acc1a = __builtin_amdgcn_mfma_f32_16x16x32_bf16(a0, wfrag[32+2*kc],   acc1a, 0,0,0);
            acc1b = __builtin_amdgcn_mfma_f32_16x16x32_bf16(a1, wfrag[32+2*kc+1], acc1b, 0,0,0);
        }

        // C/D frag: row = quad*4 + r (batch within wave tile), col = l15 (gate-col)
        #pragma unroll
        for (int r = 0; r < 4; ++r)
            gates[(wave * 16 + quad * 4 + r) * 17 + l15] =
                acc0a[r] + acc0b[r] + acc1a[r] + acc1b[r];
        __syncthreads();
        {
            float gi = gates[pb * 17 + phl * 4 + 0] + bias_i;
            float gf = gates[pb * 17 + phl * 4 + 1] + bias_f;
            float gc = gates[pb * 17 + phl * 4 + 2] + bias_c;
            float go = gates[pb * 17 + phl * 4 + 3] + bias_o;
            float it = 1.f / (1.f + __expf(-gi));
            float ft = 1.f / (1.f + __expf(-gf));
            float ch = tanhf(gc);
            float ot = 1.f / (1.f + __expf(-go));
            c_reg = ft * c_reg + it * ch;
            float hn = ot * tanhf(c_reg);
            ((__bf16*)&hstage[pb])[phl] = (__bf16)hn;
            __builtin_nontemporal_store(hn, &out[((size_t)pb * 512 + t) * 1024 + hcol]);
            if (t == 511) {
                __builtin_nontemporal_store(hn,    &out[OUT_HT + pb * 1024 + hcol]);
                __builtin_nontemporal_store(c_reg, &out[OUT_CT + pb * 1024 + hcol]);
            }
        }
        __syncthreads();   // hstage complete
        if (t < 511) {
            if (tid < 64) {
                // h(t+1) row tid, cols blk*4..+3 -> slot (t+1)&63
                u64 hv = hstage[tid];
                __hip_atomic_store(((u64*)(ring + (size_t)((t + 1) & 63) * 65536))
                                       + tid * 256 + blk,
                                   hv, __ATOMIC_RELAXED, __HIP_MEMORY_SCOPE_AGENT);
            }
            __builtin_amdgcn_s_waitcnt(0);   // h stores at coherence point
            __syncthreads();
            if (tid == 0)
                __hip_atomic_fetch_add(&bar[(blk & 63) * 16], 1,
                                       __ATOMIC_RELAXED, __HIP_MEMORY_SCOPE_AGENT);
        }
    }
}

extern "C" void kernel_launch(void* const* d_in, const int* in_sizes, int n_in,
                              void* d_out, int out_size, void* d_ws, size_t ws_size,
                              hipStream_t stream) {
    const float* x   = (const float*)d_in[0];
    const float* Wxi = (const float*)d_in[1];
    const float* Whi = (const float*)d_in[2];
    const float* bi  = (const float*)d_in[3];
    const float* Wxf = (const float*)d_in[4];
    const float* Whf = (const float*)d_in[5];
    const float* bfg = (const float*)d_in[6];
    const float* Wxc = (const float*)d_in[7];
    const float* Whc = (const float*)d_in[8];
    const float* bc  = (const float*)d_in[9];
    const float* Wxo = (const float*)d_in[10];
    const float* Who = (const float*)d_in[11];
    const float* bo  = (const float*)d_in[12];
    float* out = (float*)d_out;

    char* ws = (char*)d_ws;
    __bf16* wcombF = (__bf16*)ws;                        // 16 MB
    __bf16* xbf    = (__bf16*)(ws + (16ll << 20));       // 64 MB
    __bf16* ring   = (__bf16*)(ws + (80ll << 20));       // 64 slots x 128 KB = 8 MB
    int*    bar    = (int*)(ws + (88ll << 20));          // 64 x 64B

    hipMemsetAsync(bar, 0, 64 * 64, stream);

    hipLaunchKernelGGL(convert_x, dim3(32768), dim3(256), 0, stream,
                       (const float4*)x, (bf16x4*)xbf);
    hipLaunchKernelGGL(build_w, dim3(32768), dim3(256), 0, stream,
                       Wxi, Whi, Wxf, Whf, Wxc, Whc, Wxo, Who, wcombF);

    hipLaunchKernelGGL(lstm_rnn, dim3(256), dim3(256), 0, stream,
                       xbf, wcombF, bi, bfg, bc, bo, ring, bar, out);
}